// Round 5
// baseline (408.276 us; speedup 1.0000x reference)
//
#include <hip/hip_runtime.h>
#include <math.h>

#define T_LEN   720
#define V_DIM   64
#define KBINS   4
#define NKNOTS  4
#define BLOCK   576     // 9 waves
#define TSLICE  5       // 144 t-threads per v-group * 5 = 720
#define VB      16      // v's per block (quarter split)
#define YSTRIDE 20      // bf16 row stride (40 B): 8B-aligned uint2 slots, spread banks

// ws float offsets (kernel A -> kernel B)
#define WS_TABC 0       // [720][4] cos
#define WS_TABS 2880    // [720][4] sin
#define WS_SR   5760    // [64][4] Re(scale)-1
#define WS_SI   6016    // [64][4] Im(scale)
#define WS_KN   6272    // [64][4] clipped knots
#define WS_END  6528    // 26,112 bytes total

__device__ __forceinline__ unsigned f2bf_rne(float f) {
    unsigned u = __float_as_uint(f);
    return (u + 0x7FFFu + ((u >> 16) & 1u)) >> 16;
}
__device__ __forceinline__ float bf2f(unsigned h) {
    return __uint_as_float(h << 16);
}

// ---- Kernel A: one-time tables (removes all transcendentals from kernel B) ----
__global__ __launch_bounds__(256) void precompute_kernel(
    const float* __restrict__ a, const float* __restrict__ phi,
    const float* __restrict__ env_knots, const int* __restrict__ k_bins,
    float* __restrict__ ws)
{
    int id = blockIdx.x * 256 + threadIdx.x;
    if (id < T_LEN * KBINS) {
        int t = id >> 2, k = id & 3;
        int kb = k_bins[k];
        int m  = (kb * t) % T_LEN;                       // exact integer angle reduction
        float th = (float)m * 0.00872664625997164788f;   // 2*pi/720
        float sn, cs;
        sincosf(th, &sn, &cs);
        ws[WS_TABC + id] = cs;                           // id == t*4+k
        ws[WS_TABS + id] = sn;
    } else if (id < T_LEN * KBINS + V_DIM * KBINS) {
        int e = id - T_LEN * KBINS;                      // v*4+k
        float amp = 1.0f + a[e];
        float ph  = tanhf(phi[e]) * 0.25f;
        float sp, cp;
        sincosf(ph, &sp, &cp);
        ws[WS_SR + e] = amp * cp - 1.0f;
        ws[WS_SI + e] = amp * sp;
    } else if (id < T_LEN * KBINS + V_DIM * KBINS + V_DIM * NKNOTS) {
        int e = id - T_LEN * KBINS - V_DIM * KBINS;      // v*4+n
        ws[WS_KN + e] = fminf(fmaxf(env_knots[e], 0.5f), 1.5f);
    }
}

// ---- Kernel B: per-(b, v-quarter) DFT edit + envelope ----
// LDS ~53 KB -> 3 blocks/CU, 27 waves (84% occupancy); phases overlap across blocks.
__global__ __launch_bounds__(BLOCK, 7) void SeasonalEnvelopeAdapter_kernel(
    const float* __restrict__ y,
    const float* __restrict__ ws,
    float* __restrict__ out,
    int swz)                       // 1: XCD-aware sibling grouping (B%8==0)
{
    __shared__ __align__(16) float tabcs[2 * T_LEN * 4];            // 23,040 B
    __shared__ __align__(16) unsigned short ylds[T_LEN][YSTRIDE];   // 28,800 B
    __shared__ float sums[4][33];                                   // 528 B
    __shared__ __align__(16) float coefT[8][VB];                    // 512 B

    const int tid = threadIdx.x;
    int b, q;
    if (swz) {        // siblings (b, q=0..3) -> same XCD (consecutive blockIdx mod 8 equal)
        int P = blockIdx.x;
        int xcd = P & 7, slot = P >> 3;
        q = slot & 3;
        b = ((slot >> 2) << 3) | xcd;
    } else {
        b = blockIdx.x >> 2;
        q = blockIdx.x & 3;
    }
    const int vbase = q * VB;
    const int g    = tid & 3;       // v-group (4 v's) within the block's 16
    const int s    = tid >> 2;      // t-slice 0..143
    const int lane = tid & 63;
    const int t0   = s * TSLICE;

    // ---- Phase 0: copy trig tables ws->LDS (float4), zero sums ----
    for (int e = tid; e < 1440; e += BLOCK)
        ((float4*)tabcs)[e] = ((const float4*)ws)[e];
    if (tid < 132) ((float*)sums)[tid] = 0.f;
    __syncthreads();

    // ---- Phase 1: stream y, accumulate DFT (f32), stash bf16 copy in LDS ----
    const size_t base = (size_t)b * (T_LEN * V_DIM) + (size_t)(vbase + (g << 2));
    float accre[4][4], accim[4][4];
    #pragma unroll
    for (int j = 0; j < 4; ++j)
        #pragma unroll
        for (int k = 0; k < 4; ++k) { accre[j][k] = 0.f; accim[j][k] = 0.f; }

    #pragma unroll
    for (int i = 0; i < TSLICE; ++i) {
        int t = t0 + i;
        float4 yv = *(const float4*)(y + base + (size_t)t * V_DIM);
        uint2 p;
        p.x = f2bf_rne(yv.x) | (f2bf_rne(yv.y) << 16);
        p.y = f2bf_rne(yv.z) | (f2bf_rne(yv.w) << 16);
        *(uint2*)(&ylds[t][g << 2]) = p;
        float4 c4 = *(const float4*)(&tabcs[t << 2]);
        float4 s4 = *(const float4*)(&tabcs[WS_TABS + (t << 2)]);
        const float cs[4] = {c4.x, c4.y, c4.z, c4.w};
        const float sn[4] = {s4.x, s4.y, s4.z, s4.w};
        const float yj[4] = {yv.x, yv.y, yv.z, yv.w};
        #pragma unroll
        for (int j = 0; j < 4; ++j)
            #pragma unroll
            for (int k = 0; k < 4; ++k) {
                accre[j][k] = fmaf(yj[j], cs[k], accre[j][k]);
                accim[j][k] = fmaf(yj[j], sn[k], accim[j][k]);
            }
    }

    // ---- Reduce: butterfly over the 16 same-g lanes, then per-wave atomics ----
    #pragma unroll
    for (int j = 0; j < 4; ++j)
        #pragma unroll
        for (int k = 0; k < 4; ++k) {
            float r = accre[j][k], im = accim[j][k];
            r  += __shfl_xor(r, 4, 64);  r  += __shfl_xor(r, 8, 64);
            r  += __shfl_xor(r, 16, 64); r  += __shfl_xor(r, 32, 64);
            im += __shfl_xor(im, 4, 64); im += __shfl_xor(im, 8, 64);
            im += __shfl_xor(im, 16, 64); im += __shfl_xor(im, 32, 64);
            accre[j][k] = r; accim[j][k] = im;
        }
    if (lane < 4) {   // lane == g for lanes 0..3
        #pragma unroll
        for (int j = 0; j < 4; ++j)
            #pragma unroll
            for (int k = 0; k < 4; ++k) {
                atomicAdd(&sums[lane][j * 8 + k],     accre[j][k]);
                atomicAdd(&sums[lane][j * 8 + 4 + k], accim[j][k]);
            }
    }
    __syncthreads();

    // ---- Apply (scale-1): C = (cr - i*ci) * (sr + i*si), sr = Re(scale)-1 ----
    if (tid < 64) {
        int vl = tid >> 2, k = tid & 3;
        int gg = vl >> 2, j = vl & 3;
        float cr = sums[gg][j * 8 + k];
        float ci = sums[gg][j * 8 + 4 + k];
        int vg = vbase + vl;
        float sr = ws[WS_SR + vg * 4 + k];
        float si = ws[WS_SI + vg * 4 + k];
        const float sc = 2.0f / (float)T_LEN;
        coefT[k][vl]     = (cr * sr + ci * si) * sc;   // Re C * 2/T
        coefT[4 + k][vl] = (cr * si - ci * sr) * sc;   // Im C * 2/T
    }
    __syncthreads();

    // ---- Phase 2: reconstruct from LDS bf16 y + envelope, store ----
    float cre[4][4], cim[4][4], knr[4][4];
    #pragma unroll
    for (int k = 0; k < 4; ++k) {
        float4 r4 = *(const float4*)(&coefT[k][g << 2]);
        float4 i4 = *(const float4*)(&coefT[4 + k][g << 2]);
        cre[k][0] = r4.x; cre[k][1] = r4.y; cre[k][2] = r4.z; cre[k][3] = r4.w;
        cim[k][0] = i4.x; cim[k][1] = i4.y; cim[k][2] = i4.z; cim[k][3] = i4.w;
    }
    #pragma unroll
    for (int j = 0; j < 4; ++j) {
        float4 k4 = *(const float4*)(ws + WS_KN + (size_t)(vbase + (g << 2) + j) * 4);
        knr[j][0] = k4.x; knr[j][1] = k4.y; knr[j][2] = k4.z; knr[j][3] = k4.w;
    }

    const float posScale = 3.0f / 719.0f;
    #pragma unroll
    for (int i = 0; i < TSLICE; ++i) {
        int t = t0 + i;
        uint2 p = *(const uint2*)(&ylds[t][g << 2]);
        const float yj[4] = { bf2f(p.x & 0xFFFFu), bf2f(p.x >> 16),
                              bf2f(p.y & 0xFFFFu), bf2f(p.y >> 16) };
        float4 c4 = *(const float4*)(&tabcs[t << 2]);
        float4 s4 = *(const float4*)(&tabcs[WS_TABS + (t << 2)]);
        const float cs[4] = {c4.x, c4.y, c4.z, c4.w};
        const float sn[4] = {s4.x, s4.y, s4.z, s4.w};
        float pos = (float)t * posScale;
        int idx = (int)pos; idx = idx > 2 ? 2 : idx;
        float frac = pos - (float)idx;
        float oj[4];
        #pragma unroll
        for (int j = 0; j < 4; ++j) {
            float d = 0.f;
            #pragma unroll
            for (int k = 0; k < 4; ++k)
                d = fmaf(cre[k][j], cs[k], fmaf(-cim[k][j], sn[k], d));
            float e0 = (idx == 0) ? knr[j][0] : ((idx == 1) ? knr[j][1] : knr[j][2]);
            float e1 = (idx == 0) ? knr[j][1] : ((idx == 1) ? knr[j][2] : knr[j][3]);
            float env = fmaf(e1 - e0, frac, e0);
            oj[j] = (yj[j] + d) * env;
        }
        float4 o; o.x = oj[0]; o.y = oj[1]; o.z = oj[2]; o.w = oj[3];
        *(float4*)(out + base + (size_t)t * V_DIM) = o;
    }
}

extern "C" void kernel_launch(void* const* d_in, const int* in_sizes, int n_in,
                              void* d_out, int out_size, void* d_ws, size_t ws_size,
                              hipStream_t stream) {
    const float* y         = (const float*)d_in[0];
    const float* a         = (const float*)d_in[1];
    const float* phi       = (const float*)d_in[2];
    const float* env_knots = (const float*)d_in[3];
    const int*   k_bins    = (const int*)d_in[4];
    float* out = (float*)d_out;
    float* ws  = (float*)d_ws;

    int B = in_sizes[0] / (T_LEN * V_DIM);
    int ids = T_LEN * KBINS + V_DIM * KBINS + V_DIM * NKNOTS;
    precompute_kernel<<<(ids + 255) / 256, 256, 0, stream>>>(a, phi, env_knots, k_bins, ws);
    int swz = (B % 8 == 0) ? 1 : 0;
    SeasonalEnvelopeAdapter_kernel<<<B * 4, BLOCK, 0, stream>>>(y, ws, out, swz);
}

// Round 7
// 238.564 us; speedup vs baseline: 1.7114x; 1.7114x over previous
//
#include <hip/hip_runtime.h>
#include <math.h>

#define T_LEN   720
#define V_DIM   64
#define KBINS   4
#define NKNOTS  4
#define BLOCK   512     // 8 waves

// ws float offsets (kernel A -> kernel B)
#define WS_TAB  0       // [720][8] = {cos k0..3, sin k0..3} per t
#define WS_SR   5760    // [4][64]  Re(scale)-1, [k][v]
#define WS_SI   6016    // [4][64]  Im(scale),   [k][v]
#define WS_KN   6272    // [4][64]  clipped knots, [n][v]
#define WS_END  6528

// ---- Kernel A: one-time tables (no transcendentals in kernel B) ----
__global__ __launch_bounds__(256) void precompute_kernel(
    const float* __restrict__ a, const float* __restrict__ phi,
    const float* __restrict__ env_knots, const int* __restrict__ k_bins,
    float* __restrict__ ws)
{
    int id = blockIdx.x * 256 + threadIdx.x;
    if (id < T_LEN * KBINS) {
        int t = id >> 2, k = id & 3;
        int kb = k_bins[k];
        int m  = (kb * t) % T_LEN;                       // exact integer angle reduction
        float th = (float)m * 0.00872664625997164788f;   // 2*pi/720
        float sn, cs;
        sincosf(th, &sn, &cs);
        ws[WS_TAB + t * 8 + k]     = cs;
        ws[WS_TAB + t * 8 + 4 + k] = sn;
    } else if (id < T_LEN * KBINS + V_DIM * KBINS) {
        int e = id - T_LEN * KBINS;                      // v*4+k
        int v = e >> 2, k = e & 3;
        float amp = 1.0f + a[e];
        float ph  = tanhf(phi[e]) * 0.25f;
        float sp, cp;
        sincosf(ph, &sp, &cp);
        ws[WS_SR + k * V_DIM + v] = amp * cp - 1.0f;
        ws[WS_SI + k * V_DIM + v] = amp * sp;
    } else if (id < T_LEN * KBINS + V_DIM * KBINS + V_DIM * NKNOTS) {
        int e = id - T_LEN * KBINS - V_DIM * KBINS;      // v*4+n
        int v = e >> 2, n = e & 3;
        ws[WS_KN + n * V_DIM + v] = fminf(fmaxf(env_knots[e], 0.5f), 1.5f);
    }
}

// ---- Kernel B: one block per b; deterministic fixed-order reduction ----
// LDS 47.2 KB -> 3 blocks/CU = 24 waves at the natural ~84-VGPR allocation.
__global__ __launch_bounds__(BLOCK) void SeasonalEnvelopeAdapter_kernel(
    const float* __restrict__ y,
    const float* __restrict__ ws,
    float* __restrict__ out)
{
    __shared__ __align__(16) float tab[T_LEN * 8];       // 23,040 B {c0..3,s0..3}/t
    __shared__ float red[16][9][33];                     // 19,008 B (lane stride 297 = 9 mod 32 -> 16 distinct banks)
    __shared__ float sums[16][33];                       //  2,112 B
    __shared__ __align__(16) float coefT[8][V_DIM];      //  2,048 B [k][v] re / [4+k][v] im
    __shared__ __align__(16) float knT[NKNOTS][V_DIM];   //  1,024 B

    const int tid  = threadIdx.x;
    const int b    = blockIdx.x;
    const int g    = tid & 15;      // v-group: v0 = 4*g -> 256 B/row coalesced
    const int s    = tid >> 4;      // t-phase 0..31 (t = s + 32*i)
    const int lane = tid & 63;
    const int w    = tid >> 6;      // wave 0..7
    const int niter = (s < 16) ? 23 : 22;   // 720 = 32*22 + 16, wave-uniform

    // ---- Phase 0: ws tables -> LDS ----
    for (int e = tid; e < 1440; e += BLOCK)
        ((float4*)tab)[e] = ((const float4*)(ws + WS_TAB))[e];
    if (tid < NKNOTS * V_DIM) ((float*)knT)[tid] = ws[WS_KN + tid];
    __syncthreads();

    // ---- Phase 1: stream y, accumulate DFT partials ----
    const size_t base = (size_t)b * (T_LEN * V_DIM) + (size_t)(g << 2);
    float accre[4][4], accim[4][4];
    #pragma unroll
    for (int j = 0; j < 4; ++j)
        #pragma unroll
        for (int k = 0; k < 4; ++k) { accre[j][k] = 0.f; accim[j][k] = 0.f; }

    for (int i = 0; i < niter; ++i) {
        int t = s + (i << 5);
        float4 yv = *(const float4*)(y + base + (size_t)t * V_DIM);
        float4 c4 = *(const float4*)(&tab[t * 8]);
        float4 s4 = *(const float4*)(&tab[t * 8 + 4]);
        const float cs[4] = {c4.x, c4.y, c4.z, c4.w};
        const float sn[4] = {s4.x, s4.y, s4.z, s4.w};
        const float yj[4] = {yv.x, yv.y, yv.z, yv.w};
        #pragma unroll
        for (int j = 0; j < 4; ++j)
            #pragma unroll
            for (int k = 0; k < 4; ++k) {
                accre[j][k] = fmaf(yj[j], cs[k], accre[j][k]);
                accim[j][k] = fmaf(yj[j], sn[k], accim[j][k]);
            }
    }

    // ---- Reduce: shuffle over the wave's 4 s-phases, then fixed-order LDS tree ----
    #pragma unroll
    for (int j = 0; j < 4; ++j)
        #pragma unroll
        for (int k = 0; k < 4; ++k) {
            float r = accre[j][k], im = accim[j][k];
            r  += __shfl_xor(r, 16, 64);  r  += __shfl_xor(r, 32, 64);
            im += __shfl_xor(im, 16, 64); im += __shfl_xor(im, 32, 64);
            accre[j][k] = r; accim[j][k] = im;
        }
    if (lane < 16) {   // lane == g
        #pragma unroll
        for (int j = 0; j < 4; ++j)
            #pragma unroll
            for (int k = 0; k < 4; ++k) {
                red[lane][w][j * 8 + k]     = accre[j][k];
                red[lane][w][j * 8 + 4 + k] = accim[j][k];
            }
    }
    __syncthreads();
    {
        int g2 = tid >> 5, c = tid & 31;   // 16 x 32, all 512 threads
        float sum = 0.f;
        #pragma unroll
        for (int ww = 0; ww < 8; ++ww) sum += red[g2][ww][c];   // fixed order: deterministic
        sums[g2][c] = sum;
    }
    __syncthreads();

    // ---- Apply (scale-1): C = (cr - i*ci) * (sr + i*si) ----
    if (tid < 256) {
        int v = tid >> 2, k = tid & 3;
        int gg = v >> 2, j = v & 3;
        float cr = sums[gg][j * 8 + k];
        float ci = sums[gg][j * 8 + 4 + k];
        float sr = ws[WS_SR + k * V_DIM + v];
        float si = ws[WS_SI + k * V_DIM + v];
        const float sc = 2.0f / (float)T_LEN;
        coefT[k][v]     = (cr * sr + ci * si) * sc;   // Re C * 2/T
        coefT[4 + k][v] = (cr * si - ci * sr) * sc;   // Im C * 2/T
    }
    __syncthreads();

    // ---- Phase 2: re-read y (L3-hot), reconstruct + envelope, store ----
    float cre[4][4], cim[4][4];   // [k][j]
    #pragma unroll
    for (int k = 0; k < 4; ++k) {
        float4 r4 = *(const float4*)(&coefT[k][g << 2]);
        float4 i4 = *(const float4*)(&coefT[4 + k][g << 2]);
        cre[k][0] = r4.x; cre[k][1] = r4.y; cre[k][2] = r4.z; cre[k][3] = r4.w;
        cim[k][0] = i4.x; cim[k][1] = i4.y; cim[k][2] = i4.z; cim[k][3] = i4.w;
    }

    const float posScale = 3.0f / 719.0f;
    for (int i = 0; i < niter; ++i) {
        int t = s + (i << 5);
        float4 yv = *(const float4*)(y + base + (size_t)t * V_DIM);
        float4 c4 = *(const float4*)(&tab[t * 8]);
        float4 s4 = *(const float4*)(&tab[t * 8 + 4]);
        const float cs[4] = {c4.x, c4.y, c4.z, c4.w};
        const float sn[4] = {s4.x, s4.y, s4.z, s4.w};
        float pos = (float)t * posScale;
        int idx = (int)pos; idx = idx > 2 ? 2 : idx;
        float frac = pos - (float)idx;
        float4 e0v = *(const float4*)(&knT[idx][g << 2]);
        float4 e1v = *(const float4*)(&knT[idx + 1][g << 2]);
        const float e0[4] = {e0v.x, e0v.y, e0v.z, e0v.w};
        const float e1[4] = {e1v.x, e1v.y, e1v.z, e1v.w};
        const float yj[4] = {yv.x, yv.y, yv.z, yv.w};
        float oj[4];
        #pragma unroll
        for (int j = 0; j < 4; ++j) {
            float d = 0.f;
            #pragma unroll
            for (int k = 0; k < 4; ++k)
                d = fmaf(cre[k][j], cs[k], fmaf(-cim[k][j], sn[k], d));
            float env = fmaf(e1[j] - e0[j], frac, e0[j]);
            oj[j] = (yj[j] + d) * env;
        }
        float4 o; o.x = oj[0]; o.y = oj[1]; o.z = oj[2]; o.w = oj[3];
        *(float4*)(out + base + (size_t)t * V_DIM) = o;
    }
}

extern "C" void kernel_launch(void* const* d_in, const int* in_sizes, int n_in,
                              void* d_out, int out_size, void* d_ws, size_t ws_size,
                              hipStream_t stream) {
    const float* y         = (const float*)d_in[0];
    const float* a         = (const float*)d_in[1];
    const float* phi       = (const float*)d_in[2];
    const float* env_knots = (const float*)d_in[3];
    const int*   k_bins    = (const int*)d_in[4];
    float* out = (float*)d_out;
    float* ws  = (float*)d_ws;

    int B = in_sizes[0] / (T_LEN * V_DIM);
    int ids = T_LEN * KBINS + V_DIM * KBINS + V_DIM * NKNOTS;
    precompute_kernel<<<(ids + 255) / 256, 256, 0, stream>>>(a, phi, env_knots, k_bins, ws);
    SeasonalEnvelopeAdapter_kernel<<<B, BLOCK, 0, stream>>>(y, ws, out);
}